// Round 1
// baseline (663.598 us; speedup 1.0000x reference)
//
#include <hip/hip_runtime.h>
#include <hip/hip_bf16.h>
#include <math.h>

// ---------------- problem constants ----------------
#define BATCH   4096
#define NUM     13
#define NCAT    26
#define VOCAB   1000
#define EMB     16
#define DEMBED  624      // NUM*EMB + NCAT*EMB = 208 + 416
#define H1      512
#define H2      256

// ---------------- workspace layout (bytes) ----------------
// labels : BATCH*NCAT int32   =   425,984
// yfm    : BATCH f32          =    16,384
// embed  : BATCH*624 f32      = 10,223,616
// h1     : BATCH*512 f32      =  8,388,608
// h2     : BATCH*256 f32      =  4,194,304
// total ~23.2 MB
#define WS_LABELS_OFF 0
#define WS_YFM_OFF    (WS_LABELS_OFF + BATCH * NCAT * 4)
#define WS_EMBED_OFF  (WS_YFM_OFF + BATCH * 4)
#define WS_H1_OFF     (WS_EMBED_OFF + BATCH * DEMBED * 4)
#define WS_H2_OFF     (WS_H1_OFF + BATCH * H1 * 4)

// ---------------------------------------------------------------------------
// Kernel 1: one-hot scan. One wave (64 lanes) per (b, cat) row of 1000 f32.
// 426 MB total read -> HBM-bound floor of the whole problem.
// float4 loads: 250 float4 per row, 4 iterations of 64 lanes.
// The row is exactly one-hot, so "find value > 0.5" == argmax.
// ---------------------------------------------------------------------------
__global__ __launch_bounds__(256) void scan_labels_kernel(
    const float* __restrict__ cat, int* __restrict__ labels)
{
    int row  = blockIdx.x * 4 + (threadIdx.x >> 6);
    int lane = threadIdx.x & 63;
    if (row >= BATCH * NCAT) return;

    const float4* src = (const float4*)(cat + (size_t)row * VOCAB);
    int found = -1;
#pragma unroll
    for (int it = 0; it < 4; ++it) {
        int i4 = it * 64 + lane;
        if (i4 < VOCAB / 4) {
            float4 v = src[i4];
            int base = i4 * 4;
            if (v.x > 0.5f) found = base;
            if (v.y > 0.5f) found = base + 1;
            if (v.z > 0.5f) found = base + 2;
            if (v.w > 0.5f) found = base + 3;
        }
    }
#pragma unroll
    for (int off = 32; off > 0; off >>= 1)
        found = max(found, __shfl_xor(found, off));
    if (lane == 0) {
        if (found < 0) found = 0;  // safety (argmax of all-equal = 0)
        labels[row] = found;
    }
}

// ---------------------------------------------------------------------------
// Kernel 2: per-sample assembly. One 256-thread block per sample.
// Builds embed row (624 f32), computes y_fm = fm_embed + fm_sparse.
// ---------------------------------------------------------------------------
__global__ __launch_bounds__(256) void assemble_kernel(
    const float* __restrict__ numeric, const float* __restrict__ W_num,
    const float* __restrict__ b_num, const float* __restrict__ emb_tables,
    const float* __restrict__ w_fm, const float* __restrict__ b_fm,
    const int* __restrict__ labels, float* __restrict__ embed,
    float* __restrict__ yfm)
{
    int b   = blockIdx.x;
    int tid = threadIdx.x;
    __shared__ float es[DEMBED];
    __shared__ int   lab[NCAT];
    __shared__ float red[EMB];

    if (tid < NCAT) lab[tid] = labels[b * NCAT + tid];
    __syncthreads();

    float* eout = embed + (size_t)b * DEMBED;
    for (int t = tid; t < DEMBED; t += 256) {
        float v;
        if (t < NUM * EMB) {
            int j = t >> 4;
            v = numeric[b * NUM + j] * W_num[t] + b_num[t];
        } else {
            int u = t - NUM * EMB;
            int c = u >> 4, k = u & 15;
            v = emb_tables[((size_t)c * VOCAB + lab[c]) * EMB + k];
        }
        es[t]   = v;
        eout[t] = v;
    }
    __syncthreads();

    if (tid < EMB) {
        float ns = 0.f, cs = 0.f;
        for (int j = 0; j < NUM; ++j)  ns += es[j * EMB + tid];
        for (int c = 0; c < NCAT; ++c) cs += es[NUM * EMB + c * EMB + tid];
        red[tid] = ns * cs;
    }
    __syncthreads();

    if (tid == 0) {
        float y = b_fm[0];
        for (int k = 0; k < EMB; ++k)  y += red[k];
        for (int j = 0; j < NUM; ++j)  y += numeric[b * NUM + j] * w_fm[j];
        for (int c = 0; c < NCAT; ++c) y += w_fm[NUM + c * VOCAB + lab[c]];
        yfm[b] = y;
    }
}

// ---------------------------------------------------------------------------
// Kernels 3/4: fp32 GEMM, 64x64 tile, BK=16, 256 threads, 4x4 per thread.
// C[m,n] = relu(sum_k A[m,k]*B[k,n] + bias[n]). M,N,K all multiples of tile.
// LDS rows padded to 68 floats: 16B-aligned rows -> float4 (ds_read_b128)
// fragment reads; write-conflicts reduced to 2-way (free on gfx950).
// ---------------------------------------------------------------------------
template <int RELU>
__global__ __launch_bounds__(256) void gemm_bias_relu_kernel(
    const float* __restrict__ A, const float* __restrict__ Bm,
    const float* __restrict__ bias, float* __restrict__ C,
    int M, int N, int K)
{
    __shared__ float As[16][68];
    __shared__ float Bs[16][68];

    int tid = threadIdx.x;
    int tx  = tid & 15;   // output-col group (4 cols)
    int ty  = tid >> 4;   // output-row group (4 rows)
    int bm  = blockIdx.y * 64;
    int bn  = blockIdx.x * 64;

    float acc[4][4] = {};

    for (int k0 = 0; k0 < K; k0 += 16) {
        // stage A tile (64 rows x 16 k), transposed into As[k][m]
        {
            int kk = tid & 15;
            int m0 = tid >> 4;
#pragma unroll
            for (int r = 0; r < 4; ++r) {
                int m = m0 + r * 16;
                As[kk][m] = A[(size_t)(bm + m) * K + k0 + kk];
            }
        }
        // stage B tile (16 k x 64 n)
        {
            int n   = tid & 63;
            int kk0 = tid >> 6;
#pragma unroll
            for (int r = 0; r < 4; ++r) {
                int kk = kk0 + r * 4;
                Bs[kk][n] = Bm[(size_t)(k0 + kk) * N + bn + n];
            }
        }
        __syncthreads();

#pragma unroll
        for (int k = 0; k < 16; ++k) {
            float4 a4 = *(const float4*)&As[k][ty * 4];
            float4 b4 = *(const float4*)&Bs[k][tx * 4];
            float ra[4] = {a4.x, a4.y, a4.z, a4.w};
            float rb[4] = {b4.x, b4.y, b4.z, b4.w};
#pragma unroll
            for (int i = 0; i < 4; ++i)
#pragma unroll
                for (int j = 0; j < 4; ++j)
                    acc[i][j] += ra[i] * rb[j];
        }
        __syncthreads();
    }

#pragma unroll
    for (int i = 0; i < 4; ++i) {
        int m = bm + ty * 4 + i;
#pragma unroll
        for (int j = 0; j < 4; ++j) {
            int n = bn + tx * 4 + j;
            float v = acc[i][j] + bias[n];
            if (RELU) v = fmaxf(v, 0.f);
            C[(size_t)m * N + n] = v;
        }
    }
}

// ---------------------------------------------------------------------------
// Kernel 5: final layer. One wave per sample: dot(h2[b], W3) (256 elements),
// + b3, relu, + y_fm, sigmoid.
// ---------------------------------------------------------------------------
__global__ __launch_bounds__(256) void final_kernel(
    const float* __restrict__ h2, const float* __restrict__ W3,
    const float* __restrict__ b3, const float* __restrict__ yfm,
    float* __restrict__ out)
{
    int b    = blockIdx.x * 4 + (threadIdx.x >> 6);
    int lane = threadIdx.x & 63;
    if (b >= BATCH) return;

    const float* row = h2 + (size_t)b * H2;
    float acc = 0.f;
#pragma unroll
    for (int r = 0; r < 4; ++r)
        acc += row[lane + r * 64] * W3[lane + r * 64];
#pragma unroll
    for (int off = 32; off > 0; off >>= 1)
        acc += __shfl_xor(acc, off);
    if (lane == 0) {
        float yd = fmaxf(acc + b3[0], 0.f);
        float x  = yfm[b] + yd;
        out[b] = 1.f / (1.f + expf(-x));
    }
}

// ---------------------------------------------------------------------------
extern "C" void kernel_launch(void* const* d_in, const int* in_sizes, int n_in,
                              void* d_out, int out_size, void* d_ws, size_t ws_size,
                              hipStream_t stream)
{
    const float* numeric  = (const float*)d_in[0];
    const float* cat      = (const float*)d_in[1];
    const float* W_num    = (const float*)d_in[2];
    const float* b_num    = (const float*)d_in[3];
    const float* emb_tab  = (const float*)d_in[4];
    const float* w_fm     = (const float*)d_in[5];
    const float* b_fm     = (const float*)d_in[6];
    const float* W1       = (const float*)d_in[7];
    const float* b1       = (const float*)d_in[8];
    const float* W2       = (const float*)d_in[9];
    const float* b2       = (const float*)d_in[10];
    const float* W3       = (const float*)d_in[11];
    const float* b3       = (const float*)d_in[12];
    float* out = (float*)d_out;

    char* ws = (char*)d_ws;
    int*   labels = (int*)  (ws + WS_LABELS_OFF);
    float* yfm    = (float*)(ws + WS_YFM_OFF);
    float* embed  = (float*)(ws + WS_EMBED_OFF);
    float* h1     = (float*)(ws + WS_H1_OFF);
    float* h2     = (float*)(ws + WS_H2_OFF);

    // 1) one-hot scan: 4096*26 rows, 1 wave each, 4 waves/block
    {
        int rows = BATCH * NCAT;
        int blocks = (rows + 3) / 4;
        scan_labels_kernel<<<blocks, 256, 0, stream>>>(cat, labels);
    }
    // 2) assemble embed + y_fm
    assemble_kernel<<<BATCH, 256, 0, stream>>>(
        numeric, W_num, b_num, emb_tab, w_fm, b_fm, labels, embed, yfm);
    // 3) h1 = relu(embed @ W1 + b1)   M=4096 N=512 K=624
    {
        dim3 grid(H1 / 64, BATCH / 64);
        gemm_bias_relu_kernel<1><<<grid, 256, 0, stream>>>(
            embed, W1, b1, h1, BATCH, H1, DEMBED);
    }
    // 4) h2 = relu(h1 @ W2 + b2)      M=4096 N=256 K=512
    {
        dim3 grid(H2 / 64, BATCH / 64);
        gemm_bias_relu_kernel<1><<<grid, 256, 0, stream>>>(
            h1, W2, b2, h2, BATCH, H2, H1);
    }
    // 5) final: y_deep + y_fm -> sigmoid
    final_kernel<<<BATCH / 4, 256, 0, stream>>>(h2, W3, b3, yfm, out);
}

// Round 2
// 581.362 us; speedup vs baseline: 1.1415x; 1.1415x over previous
//
#include <hip/hip_runtime.h>
#include <math.h>

// ---------------- problem constants ----------------
#define BATCH   4096
#define NUM     13
#define NCAT    26
#define VOCAB   1000
#define EMB     16
#define DEMBED  624      // NUM*EMB + NCAT*EMB = 208 + 416
#define KPAD    640      // DEMBED padded to multiple of 32 for BK=32 MFMA loop
#define H1      512
#define H2      256

typedef unsigned short ushort_t;
typedef __attribute__((ext_vector_type(8))) short bf16x8;
typedef __attribute__((ext_vector_type(4))) float f32x4;

// ---------------- workspace layout (bytes) ----------------
#define WS_LABELS_OFF 0                                    // 4096*26*4   = 425984
#define WS_YFM_OFF    (WS_LABELS_OFF + BATCH * NCAT * 4)   // +16384
#define WS_EMBED_OFF  (WS_YFM_OFF + BATCH * 4)             // bf16 4096*640 = 5242880
#define WS_H1_OFF     (WS_EMBED_OFF + BATCH * KPAD * 2)    // bf16 4096*512 = 4194304
#define WS_H2_OFF     (WS_H1_OFF + BATCH * H1 * 2)         // f32  4096*256 = 4194304
#define WS_W1T_OFF    (WS_H2_OFF + BATCH * H2 * 4)         // bf16 512*640  = 655360
#define WS_W2T_OFF    (WS_W1T_OFF + H1 * KPAD * 2)         // bf16 256*512  = 262144

__device__ __forceinline__ ushort_t f2bf(float f) {
    union { float f; unsigned int u; } v; v.f = f;
    unsigned int r = v.u + 0x7FFFu + ((v.u >> 16) & 1u);   // round-nearest-even
    return (ushort_t)(r >> 16);
}

// ---------------------------------------------------------------------------
// Kernel 1: one-hot scan with early exit. One wave per (b,cat) row of 1000 f32.
// Chunks of 256 floats (64 lanes x float4); ballot-break once the 1.0 is found.
// Avg bytes read ~63% of 426 MB.
// ---------------------------------------------------------------------------
__global__ __launch_bounds__(256) void scan_labels_kernel(
    const float* __restrict__ cat, int* __restrict__ labels)
{
    int row  = blockIdx.x * 4 + (threadIdx.x >> 6);
    int lane = threadIdx.x & 63;
    if (row >= BATCH * NCAT) return;

    const float4* src = (const float4*)(cat + (size_t)row * VOCAB);
    int found = -1;
    for (int it = 0; it < 4; ++it) {
        int i4 = it * 64 + lane;
        if (i4 < VOCAB / 4) {
            float4 v = src[i4];
            int base = i4 * 4;
            if (v.x > 0.5f) found = base;
            if (v.y > 0.5f) found = base + 1;
            if (v.z > 0.5f) found = base + 2;
            if (v.w > 0.5f) found = base + 3;
        }
        if (__ballot(found >= 0)) break;   // wave-uniform early exit
    }
#pragma unroll
    for (int off = 32; off > 0; off >>= 1)
        found = max(found, __shfl_xor(found, off));
    if (lane == 0) {
        if (found < 0) found = 0;
        labels[row] = found;
    }
}

// ---------------------------------------------------------------------------
// Kernel 2: per-sample assembly. Builds bf16 embed row (640, zero-padded tail),
// computes y_fm = fm_embed + fm_sparse.
// ---------------------------------------------------------------------------
__global__ __launch_bounds__(256) void assemble_kernel(
    const float* __restrict__ numeric, const float* __restrict__ W_num,
    const float* __restrict__ b_num, const float* __restrict__ emb_tables,
    const float* __restrict__ w_fm, const float* __restrict__ b_fm,
    const int* __restrict__ labels, ushort_t* __restrict__ embedB,
    float* __restrict__ yfm)
{
    int b   = blockIdx.x;
    int tid = threadIdx.x;
    __shared__ float es[DEMBED];
    __shared__ int   lab[NCAT];
    __shared__ float red[EMB];

    if (tid < NCAT) lab[tid] = labels[b * NCAT + tid];
    __syncthreads();

    ushort_t* eout = embedB + (size_t)b * KPAD;
    for (int t = tid; t < KPAD; t += 256) {
        float v = 0.f;
        if (t < NUM * EMB) {
            int j = t >> 4;
            v = numeric[b * NUM + j] * W_num[t] + b_num[t];
        } else if (t < DEMBED) {
            int u = t - NUM * EMB;
            int c = u >> 4, k = u & 15;
            v = emb_tables[((size_t)c * VOCAB + lab[c]) * EMB + k];
        }
        if (t < DEMBED) es[t] = v;
        eout[t] = f2bf(v);
    }
    __syncthreads();

    if (tid < EMB) {
        float ns = 0.f, cs = 0.f;
        for (int j = 0; j < NUM; ++j)  ns += es[j * EMB + tid];
        for (int c = 0; c < NCAT; ++c) cs += es[NUM * EMB + c * EMB + tid];
        red[tid] = ns * cs;
    }
    __syncthreads();

    if (tid == 0) {
        float y = b_fm[0];
        for (int k = 0; k < EMB; ++k)  y += red[k];
        for (int j = 0; j < NUM; ++j)  y += numeric[b * NUM + j] * w_fm[j];
        for (int c = 0; c < NCAT; ++c) y += w_fm[NUM + c * VOCAB + lab[c]];
        yfm[b] = y;
    }
}

// ---------------------------------------------------------------------------
// Weight prep: cast fp32 -> bf16 and transpose to N x K (K zero-padded for W1).
// ---------------------------------------------------------------------------
__global__ __launch_bounds__(256) void prep_w1_kernel(
    const float* __restrict__ W1, ushort_t* __restrict__ W1t)
{
    int t = blockIdx.x * 256 + threadIdx.x;     // t over 512*640
    if (t >= H1 * KPAD) return;
    int n = t / KPAD, kp = t - n * KPAD;
    float v = (kp < DEMBED) ? W1[(size_t)kp * H1 + n] : 0.f;
    W1t[t] = f2bf(v);
}

__global__ __launch_bounds__(256) void prep_w2_kernel(
    const float* __restrict__ W2, ushort_t* __restrict__ W2t)
{
    int t = blockIdx.x * 256 + threadIdx.x;     // t over 256*512
    if (t >= H2 * H1) return;
    int n = t >> 9, k = t & 511;
    W2t[t] = f2bf(W2[(size_t)k * H2 + n]);
}

// ---------------------------------------------------------------------------
// MFMA bf16 GEMM: C = relu(A @ Bt^T + bias). A: MxK bf16 row-major,
// Bt: NxK bf16 row-major. 64x64 tile, BK=32, 256 threads = 4 waves (2x2),
// each wave computes 32x32 = 2x2 sub-tiles of 16x16 via mfma_f32_16x16x32_bf16.
// Fragment layouts (HW-verified, cdna_hip_programming.md §3):
//   A-op: lane holds A[m=lane&15][k=(lane>>4)*8 + j], j=0..7  (K-contiguous)
//   B-op: lane holds B[n=lane&15][k=(lane>>4)*8 + j]          (from N x K tile)
//   C/D : col=lane&15, row=(lane>>4)*4 + reg
// ---------------------------------------------------------------------------
template <int OUT_BF16>
__global__ __launch_bounds__(256) void mfma_gemm_kernel(
    const ushort_t* __restrict__ A, const ushort_t* __restrict__ Bt,
    const float* __restrict__ bias, void* __restrict__ Cout,
    int M, int N, int K)
{
    __shared__ ushort_t As[64 * 32];
    __shared__ ushort_t Bs[64 * 32];

    int tid = threadIdx.x;
    int l   = tid & 63;
    int w   = tid >> 6;
    int wm  = w >> 1, wn = w & 1;
    int bm  = blockIdx.y * 64;
    int bn  = blockIdx.x * 64;

    // staging map: thread t stages one 16B chunk: row = t>>2, k-offset = (t&3)*8
    int srow = tid >> 2;
    int sk   = (tid & 3) * 8;

    f32x4 acc[2][2];
#pragma unroll
    for (int i = 0; i < 2; ++i)
#pragma unroll
        for (int j = 0; j < 2; ++j)
            acc[i][j] = (f32x4){0.f, 0.f, 0.f, 0.f};

    for (int k0 = 0; k0 < K; k0 += 32) {
        uint4 av = *(const uint4*)&A [(size_t)(bm + srow) * K + k0 + sk];
        uint4 bv = *(const uint4*)&Bt[(size_t)(bn + srow) * K + k0 + sk];
        __syncthreads();   // previous iteration's LDS reads complete
        *(uint4*)&As[tid * 8] = av;
        *(uint4*)&Bs[tid * 8] = bv;
        __syncthreads();

        bf16x8 af[2], bfr[2];
#pragma unroll
        for (int i = 0; i < 2; ++i)
            af[i] = *(const bf16x8*)&As[(wm * 32 + i * 16 + (l & 15)) * 32 + (l >> 4) * 8];
#pragma unroll
        for (int j = 0; j < 2; ++j)
            bfr[j] = *(const bf16x8*)&Bs[(wn * 32 + j * 16 + (l & 15)) * 32 + (l >> 4) * 8];
#pragma unroll
        for (int i = 0; i < 2; ++i)
#pragma unroll
            for (int j = 0; j < 2; ++j)
                acc[i][j] = __builtin_amdgcn_mfma_f32_16x16x32_bf16(
                    af[i], bfr[j], acc[i][j], 0, 0, 0);
    }

#pragma unroll
    for (int i = 0; i < 2; ++i) {
        int row0 = bm + wm * 32 + i * 16 + (l >> 4) * 4;
#pragma unroll
        for (int j = 0; j < 2; ++j) {
            int col = bn + wn * 32 + j * 16 + (l & 15);
            float bv = bias[col];
#pragma unroll
            for (int r = 0; r < 4; ++r) {
                float v = acc[i][j][r] + bv;
                v = fmaxf(v, 0.f);
                if (OUT_BF16)
                    ((ushort_t*)Cout)[(size_t)(row0 + r) * N + col] = f2bf(v);
                else
                    ((float*)Cout)[(size_t)(row0 + r) * N + col] = v;
            }
        }
    }
}

// ---------------------------------------------------------------------------
// Kernel 5: final layer. One wave per sample: dot(h2[b], W3) (256 elems),
// + b3, relu, + y_fm, sigmoid.
// ---------------------------------------------------------------------------
__global__ __launch_bounds__(256) void final_kernel(
    const float* __restrict__ h2, const float* __restrict__ W3,
    const float* __restrict__ b3, const float* __restrict__ yfm,
    float* __restrict__ out)
{
    int b    = blockIdx.x * 4 + (threadIdx.x >> 6);
    int lane = threadIdx.x & 63;
    if (b >= BATCH) return;

    const float* row = h2 + (size_t)b * H2;
    float acc = 0.f;
#pragma unroll
    for (int r = 0; r < 4; ++r)
        acc += row[lane + r * 64] * W3[lane + r * 64];
#pragma unroll
    for (int off = 32; off > 0; off >>= 1)
        acc += __shfl_xor(acc, off);
    if (lane == 0) {
        float yd = fmaxf(acc + b3[0], 0.f);
        float x  = yfm[b] + yd;
        out[b] = 1.f / (1.f + expf(-x));
    }
}

// ---------------------------------------------------------------------------
extern "C" void kernel_launch(void* const* d_in, const int* in_sizes, int n_in,
                              void* d_out, int out_size, void* d_ws, size_t ws_size,
                              hipStream_t stream)
{
    const float* numeric  = (const float*)d_in[0];
    const float* cat      = (const float*)d_in[1];
    const float* W_num    = (const float*)d_in[2];
    const float* b_num    = (const float*)d_in[3];
    const float* emb_tab  = (const float*)d_in[4];
    const float* w_fm     = (const float*)d_in[5];
    const float* b_fm     = (const float*)d_in[6];
    const float* W1       = (const float*)d_in[7];
    const float* b1       = (const float*)d_in[8];
    const float* W2       = (const float*)d_in[9];
    const float* b2       = (const float*)d_in[10];
    const float* W3       = (const float*)d_in[11];
    const float* b3       = (const float*)d_in[12];
    float* out = (float*)d_out;
    (void)ws_size; (void)in_sizes; (void)n_in; (void)out_size;

    char* ws = (char*)d_ws;
    int*      labels = (int*)     (ws + WS_LABELS_OFF);
    float*    yfm    = (float*)   (ws + WS_YFM_OFF);
    ushort_t* embedB = (ushort_t*)(ws + WS_EMBED_OFF);
    ushort_t* h1B    = (ushort_t*)(ws + WS_H1_OFF);
    float*    h2     = (float*)   (ws + WS_H2_OFF);
    ushort_t* W1t    = (ushort_t*)(ws + WS_W1T_OFF);
    ushort_t* W2t    = (ushort_t*)(ws + WS_W2T_OFF);

    // weight prep (tiny; independent of scan/assemble)
    prep_w1_kernel<<<(H1 * KPAD + 255) / 256, 256, 0, stream>>>(W1, W1t);
    prep_w2_kernel<<<(H2 * H1 + 255) / 256, 256, 0, stream>>>(W2, W2t);

    // 1) one-hot scan with early exit
    {
        int rows = BATCH * NCAT;
        scan_labels_kernel<<<(rows + 3) / 4, 256, 0, stream>>>(cat, labels);
    }
    // 2) assemble bf16 embed (padded to 640) + y_fm
    assemble_kernel<<<BATCH, 256, 0, stream>>>(
        numeric, W_num, b_num, emb_tab, w_fm, b_fm, labels, embedB, yfm);
    // 3) h1 = relu(embed @ W1 + b1)   M=4096 N=512 K=640(pad) -> bf16
    {
        dim3 grid(H1 / 64, BATCH / 64);
        mfma_gemm_kernel<1><<<grid, 256, 0, stream>>>(
            embedB, W1t, b1, (void*)h1B, BATCH, H1, KPAD);
    }
    // 4) h2 = relu(h1 @ W2 + b2)      M=4096 N=256 K=512 -> f32
    {
        dim3 grid(H2 / 64, BATCH / 64);
        mfma_gemm_kernel<0><<<grid, 256, 0, stream>>>(
            h1B, W2t, b2, (void*)h2, BATCH, H2, H1);
    }
    // 5) final: y_deep + y_fm -> sigmoid
    final_kernel<<<BATCH / 4, 256, 0, stream>>>(h2, W3, b3, yfm, out);
}

// Round 3
// 573.844 us; speedup vs baseline: 1.1564x; 1.0131x over previous
//
#include <hip/hip_runtime.h>
#include <math.h>

// ---------------- problem constants ----------------
#define BATCH   4096
#define NUM     13
#define NCAT    26
#define VOCAB   1000
#define EMB     16
#define DEMBED  624      // NUM*EMB + NCAT*EMB = 208 + 416
#define KPAD    640      // DEMBED padded to multiple of 64 for BK=64 MFMA loop
#define H1      512
#define H2      256

#define LDS_STRIDE 72    // 64 + 8 ushorts pad: 144 B rows, 16B-aligned, 2-way max conflict

typedef unsigned short ushort_t;
typedef __attribute__((ext_vector_type(8))) short bf16x8;
typedef __attribute__((ext_vector_type(4))) float f32x4;

// ---------------- workspace layout (bytes) ----------------
#define WS_LABELS_OFF 0                                    // 4096*26*4   = 425984
#define WS_YFM_OFF    (WS_LABELS_OFF + BATCH * NCAT * 4)   // +16384
#define WS_EMBED_OFF  (WS_YFM_OFF + BATCH * 4)             // bf16 4096*640 = 5242880
#define WS_H1_OFF     (WS_EMBED_OFF + BATCH * KPAD * 2)    // bf16 4096*512 = 4194304
#define WS_H2_OFF     (WS_H1_OFF + BATCH * H1 * 2)         // f32  4096*256 = 4194304
#define WS_W1T_OFF    (WS_H2_OFF + BATCH * H2 * 4)         // bf16 512*640  = 655360
#define WS_W2T_OFF    (WS_W1T_OFF + H1 * KPAD * 2)         // bf16 256*512  = 262144

__device__ __forceinline__ ushort_t f2bf(float f) {
    union { float f; unsigned int u; } v; v.f = f;
    unsigned int r = v.u + 0x7FFFu + ((v.u >> 16) & 1u);   // round-nearest-even
    return (ushort_t)(r >> 16);
}

// ---------------------------------------------------------------------------
// Kernel 1: one-hot scan with early exit. One wave per (b,cat) row of 1000 f32.
// float2 chunks (128 floats per ballot): E[bytes] ~55% of the 426 MB input.
// ---------------------------------------------------------------------------
__global__ __launch_bounds__(256) void scan_labels_kernel(
    const float* __restrict__ cat, int* __restrict__ labels)
{
    int row  = blockIdx.x * 4 + (threadIdx.x >> 6);
    int lane = threadIdx.x & 63;
    if (row >= BATCH * NCAT) return;

    const float2* src = (const float2*)(cat + (size_t)row * VOCAB);
    int found = -1;
    for (int it = 0; it < 8; ++it) {
        int i2 = it * 64 + lane;
        if (i2 < VOCAB / 2) {
            float2 v = src[i2];
            if (v.x > 0.5f) found = i2 * 2;
            if (v.y > 0.5f) found = i2 * 2 + 1;
        }
        if (__ballot(found >= 0)) break;   // wave-uniform early exit
    }
#pragma unroll
    for (int off = 32; off > 0; off >>= 1)
        found = max(found, __shfl_xor(found, off));
    if (lane == 0) {
        if (found < 0) found = 0;
        labels[row] = found;
    }
}

// ---------------------------------------------------------------------------
// Kernel 2: per-sample assembly. Builds bf16 embed row (640, zero-padded tail),
// computes y_fm = fm_embed + fm_sparse. Gather tail parallelized across lanes.
// ---------------------------------------------------------------------------
__global__ __launch_bounds__(256) void assemble_kernel(
    const float* __restrict__ numeric, const float* __restrict__ W_num,
    const float* __restrict__ b_num, const float* __restrict__ emb_tables,
    const float* __restrict__ w_fm, const float* __restrict__ b_fm,
    const int* __restrict__ labels, ushort_t* __restrict__ embedB,
    float* __restrict__ yfm)
{
    int b   = blockIdx.x;
    int tid = threadIdx.x;
    __shared__ float es[DEMBED];
    __shared__ int   lab[NCAT];
    __shared__ float red[EMB];
    __shared__ float sp[NCAT + NUM];

    if (tid < NCAT) lab[tid] = labels[b * NCAT + tid];
    __syncthreads();

    ushort_t* eout = embedB + (size_t)b * KPAD;
    for (int t = tid; t < KPAD; t += 256) {
        float v = 0.f;
        if (t < NUM * EMB) {
            int j = t >> 4;
            v = numeric[b * NUM + j] * W_num[t] + b_num[t];
        } else if (t < DEMBED) {
            int u = t - NUM * EMB;
            int c = u >> 4, k = u & 15;
            v = emb_tables[((size_t)c * VOCAB + lab[c]) * EMB + k];
        }
        if (t < DEMBED) es[t] = v;
        eout[t] = f2bf(v);
    }
    // parallel sparse-FM gathers (independent loads, latency overlapped)
    if (tid < NCAT) {
        sp[tid] = w_fm[NUM + tid * VOCAB + lab[tid]];
    } else if (tid < NCAT + NUM) {
        int j = tid - NCAT;
        sp[tid] = numeric[b * NUM + j] * w_fm[j];
    }
    __syncthreads();

    if (tid < EMB) {
        float ns = 0.f, cs = 0.f;
        for (int j = 0; j < NUM; ++j)  ns += es[j * EMB + tid];
        for (int c = 0; c < NCAT; ++c) cs += es[NUM * EMB + c * EMB + tid];
        red[tid] = ns * cs;
    }
    __syncthreads();

    if (tid == 0) {
        float y = b_fm[0];
        for (int k = 0; k < EMB; ++k)          y += red[k];
        for (int i = 0; i < NCAT + NUM; ++i)   y += sp[i];
        yfm[b] = y;
    }
}

// ---------------------------------------------------------------------------
// Weight prep: cast fp32 -> bf16 and transpose to N x K (K zero-padded for W1).
// ---------------------------------------------------------------------------
__global__ __launch_bounds__(256) void prep_w1_kernel(
    const float* __restrict__ W1, ushort_t* __restrict__ W1t)
{
    int t = blockIdx.x * 256 + threadIdx.x;     // t over 512*640
    if (t >= H1 * KPAD) return;
    int n = t / KPAD, kp = t - n * KPAD;
    float v = (kp < DEMBED) ? W1[(size_t)kp * H1 + n] : 0.f;
    W1t[t] = f2bf(v);
}

__global__ __launch_bounds__(256) void prep_w2_kernel(
    const float* __restrict__ W2, ushort_t* __restrict__ W2t)
{
    int t = blockIdx.x * 256 + threadIdx.x;     // t over 256*512
    if (t >= H2 * H1) return;
    int n = t >> 9, k = t & 511;
    W2t[t] = f2bf(W2[(size_t)k * H2 + n]);
}

// ---------------------------------------------------------------------------
// MFMA bf16 GEMM: C = relu(A @ Bt^T + bias). A: MxK bf16 row-major,
// Bt: NxK bf16 row-major. 64x64 tile, BK=64, 256 threads = 4 waves (2x2),
// each wave computes 32x32 = 2x2 sub-tiles of 16x16 via mfma_f32_16x16x32_bf16.
// LDS rows padded to 72 ushorts (144 B): fragment ds_read_b128 hits distinct
// bank groups for rows 0-7, 2-way alias for 8-15 (free on gfx950 per m136).
// Fragment layouts (HW-verified):
//   A-op: lane holds A[m=lane&15][k=(lane>>4)*8 + j], j=0..7
//   B-op: lane holds B[n=lane&15][k=(lane>>4)*8 + j]
//   C/D : col=lane&15, row=(lane>>4)*4 + reg
// ---------------------------------------------------------------------------
template <int OUT_BF16>
__global__ __launch_bounds__(256) void mfma_gemm_kernel(
    const ushort_t* __restrict__ A, const ushort_t* __restrict__ Bt,
    const float* __restrict__ bias, void* __restrict__ Cout,
    int M, int N, int K)
{
    __shared__ ushort_t As[64 * LDS_STRIDE];
    __shared__ ushort_t Bs[64 * LDS_STRIDE];

    int tid = threadIdx.x;
    int l   = tid & 63;
    int w   = tid >> 6;
    int wm  = w >> 1, wn = w & 1;
    int bm  = blockIdx.y * 64;
    int bn  = blockIdx.x * 64;

    // staging map: thread t stages 2x16B per matrix: row = t>>2,
    // k-offsets (t&3)*8 and (t&3)*8+32 (ushorts)
    int srow = tid >> 2;
    int sk   = (tid & 3) * 8;

    f32x4 acc[2][2];
#pragma unroll
    for (int i = 0; i < 2; ++i)
#pragma unroll
        for (int j = 0; j < 2; ++j)
            acc[i][j] = (f32x4){0.f, 0.f, 0.f, 0.f};

    for (int k0 = 0; k0 < K; k0 += 64) {
        const ushort_t* ap = &A [(size_t)(bm + srow) * K + k0 + sk];
        const ushort_t* bp = &Bt[(size_t)(bn + srow) * K + k0 + sk];
        uint4 av0 = *(const uint4*)ap;
        uint4 av1 = *(const uint4*)(ap + 32);
        uint4 bv0 = *(const uint4*)bp;
        uint4 bv1 = *(const uint4*)(bp + 32);
        __syncthreads();   // previous iteration's LDS reads complete
        *(uint4*)&As[srow * LDS_STRIDE + sk]      = av0;
        *(uint4*)&As[srow * LDS_STRIDE + sk + 32] = av1;
        *(uint4*)&Bs[srow * LDS_STRIDE + sk]      = bv0;
        *(uint4*)&Bs[srow * LDS_STRIDE + sk + 32] = bv1;
        __syncthreads();

#pragma unroll
        for (int s = 0; s < 2; ++s) {
            bf16x8 af[2], bfr[2];
#pragma unroll
            for (int i = 0; i < 2; ++i)
                af[i] = *(const bf16x8*)&As[(wm * 32 + i * 16 + (l & 15)) * LDS_STRIDE
                                            + s * 32 + (l >> 4) * 8];
#pragma unroll
            for (int j = 0; j < 2; ++j)
                bfr[j] = *(const bf16x8*)&Bs[(wn * 32 + j * 16 + (l & 15)) * LDS_STRIDE
                                             + s * 32 + (l >> 4) * 8];
#pragma unroll
            for (int i = 0; i < 2; ++i)
#pragma unroll
                for (int j = 0; j < 2; ++j)
                    acc[i][j] = __builtin_amdgcn_mfma_f32_16x16x32_bf16(
                        af[i], bfr[j], acc[i][j], 0, 0, 0);
        }
    }

#pragma unroll
    for (int i = 0; i < 2; ++i) {
        int row0 = bm + wm * 32 + i * 16 + (l >> 4) * 4;
#pragma unroll
        for (int j = 0; j < 2; ++j) {
            int col = bn + wn * 32 + j * 16 + (l & 15);
            float bv = bias[col];
#pragma unroll
            for (int r = 0; r < 4; ++r) {
                float v = acc[i][j][r] + bv;
                v = fmaxf(v, 0.f);
                if (OUT_BF16)
                    ((ushort_t*)Cout)[(size_t)(row0 + r) * N + col] = f2bf(v);
                else
                    ((float*)Cout)[(size_t)(row0 + r) * N + col] = v;
            }
        }
    }
}

// ---------------------------------------------------------------------------
// Kernel 5: final layer. One wave per sample: dot(h2[b], W3) (256 elems),
// + b3, relu, + y_fm, sigmoid.
// ---------------------------------------------------------------------------
__global__ __launch_bounds__(256) void final_kernel(
    const float* __restrict__ h2, const float* __restrict__ W3,
    const float* __restrict__ b3, const float* __restrict__ yfm,
    float* __restrict__ out)
{
    int b    = blockIdx.x * 4 + (threadIdx.x >> 6);
    int lane = threadIdx.x & 63;
    if (b >= BATCH) return;

    const float* row = h2 + (size_t)b * H2;
    float acc = 0.f;
#pragma unroll
    for (int r = 0; r < 4; ++r)
        acc += row[lane + r * 64] * W3[lane + r * 64];
#pragma unroll
    for (int off = 32; off > 0; off >>= 1)
        acc += __shfl_xor(acc, off);
    if (lane == 0) {
        float yd = fmaxf(acc + b3[0], 0.f);
        float x  = yfm[b] + yd;
        out[b] = 1.f / (1.f + expf(-x));
    }
}

// ---------------------------------------------------------------------------
extern "C" void kernel_launch(void* const* d_in, const int* in_sizes, int n_in,
                              void* d_out, int out_size, void* d_ws, size_t ws_size,
                              hipStream_t stream)
{
    const float* numeric  = (const float*)d_in[0];
    const float* cat      = (const float*)d_in[1];
    const float* W_num    = (const float*)d_in[2];
    const float* b_num    = (const float*)d_in[3];
    const float* emb_tab  = (const float*)d_in[4];
    const float* w_fm     = (const float*)d_in[5];
    const float* b_fm     = (const float*)d_in[6];
    const float* W1       = (const float*)d_in[7];
    const float* b1       = (const float*)d_in[8];
    const float* W2       = (const float*)d_in[9];
    const float* b2       = (const float*)d_in[10];
    const float* W3       = (const float*)d_in[11];
    const float* b3       = (const float*)d_in[12];
    float* out = (float*)d_out;
    (void)ws_size; (void)in_sizes; (void)n_in; (void)out_size;

    char* ws = (char*)d_ws;
    int*      labels = (int*)     (ws + WS_LABELS_OFF);
    float*    yfm    = (float*)   (ws + WS_YFM_OFF);
    ushort_t* embedB = (ushort_t*)(ws + WS_EMBED_OFF);
    ushort_t* h1B    = (ushort_t*)(ws + WS_H1_OFF);
    float*    h2     = (float*)   (ws + WS_H2_OFF);
    ushort_t* W1t    = (ushort_t*)(ws + WS_W1T_OFF);
    ushort_t* W2t    = (ushort_t*)(ws + WS_W2T_OFF);

    // weight prep (tiny; independent of scan/assemble)
    prep_w1_kernel<<<(H1 * KPAD + 255) / 256, 256, 0, stream>>>(W1, W1t);
    prep_w2_kernel<<<(H2 * H1 + 255) / 256, 256, 0, stream>>>(W2, W2t);

    // 1) one-hot scan with early exit (float2 granularity)
    {
        int rows = BATCH * NCAT;
        scan_labels_kernel<<<(rows + 3) / 4, 256, 0, stream>>>(cat, labels);
    }
    // 2) assemble bf16 embed (padded to 640) + y_fm
    assemble_kernel<<<BATCH, 256, 0, stream>>>(
        numeric, W_num, b_num, emb_tab, w_fm, b_fm, labels, embedB, yfm);
    // 3) h1 = relu(embed @ W1 + b1)   M=4096 N=512 K=640(pad) -> bf16
    {
        dim3 grid(H1 / 64, BATCH / 64);
        mfma_gemm_kernel<1><<<grid, 256, 0, stream>>>(
            embedB, W1t, b1, (void*)h1B, BATCH, H1, KPAD);
    }
    // 4) h2 = relu(h1 @ W2 + b2)      M=4096 N=256 K=512 -> f32
    {
        dim3 grid(H2 / 64, BATCH / 64);
        mfma_gemm_kernel<0><<<grid, 256, 0, stream>>>(
            h1B, W2t, b2, (void*)h2, BATCH, H2, H1);
    }
    // 5) final: y_deep + y_fm -> sigmoid
    final_kernel<<<BATCH / 4, 256, 0, stream>>>(h2, W3, b3, yfm, out);
}

// Round 4
// 573.706 us; speedup vs baseline: 1.1567x; 1.0002x over previous
//
#include <hip/hip_runtime.h>
#include <math.h>

// ---------------- problem constants ----------------
#define BATCH   4096
#define NUM     13
#define NCAT    26
#define VOCAB   1000
#define EMB     16
#define DEMBED  624      // NUM*EMB + NCAT*EMB = 208 + 416
#define KPAD    640      // DEMBED padded to multiple of 64 for BK=64 MFMA loop
#define H1      512
#define H2      256

#define LDS_STRIDE 72    // 64 + 8 ushorts pad: 144 B rows, 2-way max conflict (free)

typedef unsigned short ushort_t;
typedef __attribute__((ext_vector_type(8))) short bf16x8;
typedef __attribute__((ext_vector_type(4))) float f32x4;

// ---------------- workspace layout (bytes) ----------------
#define WS_YFM_OFF    0                                    // f32  4096      = 16384
#define WS_YDEEP_OFF  (WS_YFM_OFF + BATCH * 4)             // f32  4096      = 16384
#define WS_EMBED_OFF  (WS_YDEEP_OFF + BATCH * 4)           // bf16 4096*640  = 5242880
#define WS_H1_OFF     (WS_EMBED_OFF + BATCH * KPAD * 2)    // bf16 4096*512  = 4194304
#define WS_W1T_OFF    (WS_H1_OFF + BATCH * H1 * 2)         // bf16 512*640   = 655360
#define WS_W2T_OFF    (WS_W1T_OFF + H1 * KPAD * 2)         // bf16 256*512   = 262144

__device__ __forceinline__ ushort_t f2bf(float f) {
    union { float f; unsigned int u; } v; v.f = f;
    unsigned int r = v.u + 0x7FFFu + ((v.u >> 16) & 1u);   // round-nearest-even
    return (ushort_t)(r >> 16);
}

// ---------------------------------------------------------------------------
// Kernel A: merged prep — W1 cast+transpose (K zero-padded), W2 cast+transpose,
// ydeep zero-init (ws is poisoned 0xAA each call).
// ---------------------------------------------------------------------------
#define PREP_N1 (H1 * KPAD)          // 327680
#define PREP_N2 (H2 * H1)            // 131072
#define PREP_TOTAL (PREP_N1 + PREP_N2 + BATCH)

__global__ __launch_bounds__(256) void prep_kernel(
    const float* __restrict__ W1, const float* __restrict__ W2,
    ushort_t* __restrict__ W1t, ushort_t* __restrict__ W2t,
    float* __restrict__ ydeep)
{
    int t = blockIdx.x * 256 + threadIdx.x;
    if (t < PREP_N1) {
        int n = t / KPAD, kp = t - n * KPAD;
        float v = (kp < DEMBED) ? W1[(size_t)kp * H1 + n] : 0.f;
        W1t[t] = f2bf(v);
    } else if (t < PREP_N1 + PREP_N2) {
        int u = t - PREP_N1;
        int n = u >> 9, k = u & 511;
        W2t[u] = f2bf(W2[(size_t)k * H2 + n]);
    } else if (t < PREP_TOTAL) {
        ydeep[t - PREP_N1 - PREP_N2] = 0.f;
    }
}

// ---------------------------------------------------------------------------
// Kernel B: fused one-hot scan + assembly. One block per sample.
// 4 waves scan the 26 one-hot rows (early-exit, float2 granularity:
// E[bytes] ~56% of 426 MB); labels stay in LDS; then build bf16 embed row
// (640, zero tail) and y_fm.
// ---------------------------------------------------------------------------
__global__ __launch_bounds__(256) void scan_assemble_kernel(
    const float* __restrict__ cat,
    const float* __restrict__ numeric, const float* __restrict__ W_num,
    const float* __restrict__ b_num, const float* __restrict__ emb_tables,
    const float* __restrict__ w_fm, const float* __restrict__ b_fm,
    ushort_t* __restrict__ embedB, float* __restrict__ yfm)
{
    int b    = blockIdx.x;
    int tid  = threadIdx.x;
    int w    = tid >> 6;
    int lane = tid & 63;

    __shared__ float es[DEMBED];
    __shared__ int   lab[NCAT];
    __shared__ float red[EMB];
    __shared__ float sp[NCAT + NUM];

    // ---- scan: wave w handles categories w, w+4, ...
    for (int c = w; c < NCAT; c += 4) {
        const float2* src = (const float2*)(cat + ((size_t)b * NCAT + c) * VOCAB);
        int found = -1;
        for (int it = 0; it < 8; ++it) {
            int i2 = it * 64 + lane;
            if (i2 < VOCAB / 2) {
                float2 v = src[i2];
                if (v.x > 0.5f) found = i2 * 2;
                if (v.y > 0.5f) found = i2 * 2 + 1;
            }
            if (__ballot(found >= 0)) break;   // wave-uniform early exit
        }
#pragma unroll
        for (int off = 32; off > 0; off >>= 1)
            found = max(found, __shfl_xor(found, off));
        if (lane == 0) lab[c] = (found < 0) ? 0 : found;
    }
    __syncthreads();

    // ---- assemble embed row (bf16, KPAD wide) ----
    ushort_t* eout = embedB + (size_t)b * KPAD;
    for (int t = tid; t < KPAD; t += 256) {
        float v = 0.f;
        if (t < NUM * EMB) {
            int j = t >> 4;
            v = numeric[b * NUM + j] * W_num[t] + b_num[t];
        } else if (t < DEMBED) {
            int u = t - NUM * EMB;
            int c = u >> 4, k = u & 15;
            v = emb_tables[((size_t)c * VOCAB + lab[c]) * EMB + k];
        }
        if (t < DEMBED) es[t] = v;
        eout[t] = f2bf(v);
    }
    // parallel sparse-FM gathers
    if (tid < NCAT) {
        sp[tid] = w_fm[NUM + tid * VOCAB + lab[tid]];
    } else if (tid < NCAT + NUM) {
        int j = tid - NCAT;
        sp[tid] = numeric[b * NUM + j] * w_fm[j];
    }
    __syncthreads();

    if (tid < EMB) {
        float ns = 0.f, cs = 0.f;
        for (int j = 0; j < NUM; ++j)  ns += es[j * EMB + tid];
        for (int c = 0; c < NCAT; ++c) cs += es[NUM * EMB + c * EMB + tid];
        red[tid] = ns * cs;
    }
    __syncthreads();

    if (tid == 0) {
        float y = b_fm[0];
        for (int k = 0; k < EMB; ++k)          y += red[k];
        for (int i = 0; i < NCAT + NUM; ++i)   y += sp[i];
        yfm[b] = y;
    }
}

// ---------------------------------------------------------------------------
// Kernel C: MFMA bf16 GEMM1: h1 = relu(embed @ W1t^T + b1) -> bf16.
// 64x64 tile, BK=64, 4 waves (2x2), each wave 32x32 via 2x2 mfma 16x16x32.
// Fragment layouts (HW-verified):
//   A/B-op: lane holds X[m=lane&15][k=(lane>>4)*8 + j], j=0..7
//   C/D   : col=lane&15, row=(lane>>4)*4 + reg
// ---------------------------------------------------------------------------
__global__ __launch_bounds__(256) void gemm1_kernel(
    const ushort_t* __restrict__ A, const ushort_t* __restrict__ Bt,
    const float* __restrict__ bias, ushort_t* __restrict__ Cout)
{
    const int M = BATCH, N = H1, K = KPAD;
    __shared__ ushort_t As[64 * LDS_STRIDE];
    __shared__ ushort_t Bs[64 * LDS_STRIDE];

    int tid = threadIdx.x;
    int l   = tid & 63;
    int w   = tid >> 6;
    int wm  = w >> 1, wn = w & 1;
    int bm  = blockIdx.y * 64;
    int bn  = blockIdx.x * 64;

    int srow = tid >> 2;
    int sk   = (tid & 3) * 8;

    f32x4 acc[2][2];
#pragma unroll
    for (int i = 0; i < 2; ++i)
#pragma unroll
        for (int j = 0; j < 2; ++j)
            acc[i][j] = (f32x4){0.f, 0.f, 0.f, 0.f};

    for (int k0 = 0; k0 < K; k0 += 64) {
        const ushort_t* ap = &A [(size_t)(bm + srow) * K + k0 + sk];
        const ushort_t* bp = &Bt[(size_t)(bn + srow) * K + k0 + sk];
        uint4 av0 = *(const uint4*)ap;
        uint4 av1 = *(const uint4*)(ap + 32);
        uint4 bv0 = *(const uint4*)bp;
        uint4 bv1 = *(const uint4*)(bp + 32);
        __syncthreads();
        *(uint4*)&As[srow * LDS_STRIDE + sk]      = av0;
        *(uint4*)&As[srow * LDS_STRIDE + sk + 32] = av1;
        *(uint4*)&Bs[srow * LDS_STRIDE + sk]      = bv0;
        *(uint4*)&Bs[srow * LDS_STRIDE + sk + 32] = bv1;
        __syncthreads();

#pragma unroll
        for (int s = 0; s < 2; ++s) {
            bf16x8 af[2], bfr[2];
#pragma unroll
            for (int i = 0; i < 2; ++i)
                af[i] = *(const bf16x8*)&As[(wm * 32 + i * 16 + (l & 15)) * LDS_STRIDE
                                            + s * 32 + (l >> 4) * 8];
#pragma unroll
            for (int j = 0; j < 2; ++j)
                bfr[j] = *(const bf16x8*)&Bs[(wn * 32 + j * 16 + (l & 15)) * LDS_STRIDE
                                             + s * 32 + (l >> 4) * 8];
#pragma unroll
            for (int i = 0; i < 2; ++i)
#pragma unroll
                for (int j = 0; j < 2; ++j)
                    acc[i][j] = __builtin_amdgcn_mfma_f32_16x16x32_bf16(
                        af[i], bfr[j], acc[i][j], 0, 0, 0);
        }
    }

#pragma unroll
    for (int i = 0; i < 2; ++i) {
        int row0 = bm + wm * 32 + i * 16 + (l >> 4) * 4;
#pragma unroll
        for (int j = 0; j < 2; ++j) {
            int col = bn + wn * 32 + j * 16 + (l & 15);
            float bv = bias[col];
#pragma unroll
            for (int r = 0; r < 4; ++r) {
                float v = fmaxf(acc[i][j][r] + bv, 0.f);
                Cout[(size_t)(row0 + r) * N + col] = f2bf(v);
            }
        }
    }
}

// ---------------------------------------------------------------------------
// Kernel D: fused GEMM2 + W3 dot. h2 never materializes.
// 32x64 tile (grid 4 x 128 = 512 blocks, 2/CU), BK=64, 4 waves:
// wave w: row-tile i=w>>1 (16 rows), cols (w&1)*32 + 2x16.
// Epilogue: s = sum_j relu(acc+b2)*W3[col]; 16-lane shuffle-reduce;
// atomicAdd into ydeep[row] (zeroed by prep). ReLU is per-element of h2,
// so N-split partial dots are exact.
// ---------------------------------------------------------------------------
__global__ __launch_bounds__(256) void gemm2_dot_kernel(
    const ushort_t* __restrict__ A, const ushort_t* __restrict__ Bt,
    const float* __restrict__ bias, const float* __restrict__ W3,
    float* __restrict__ ydeep)
{
    const int N = H2, K = H1;
    __shared__ ushort_t As[32 * LDS_STRIDE];
    __shared__ ushort_t Bs[64 * LDS_STRIDE];

    int tid = threadIdx.x;
    int l   = tid & 63;
    int w   = tid >> 6;
    int it  = w >> 1;               // row-tile index (0..1)
    int cb  = (w & 1) * 32;         // col base within tile
    int bm  = blockIdx.y * 32;
    int bn  = blockIdx.x * 64;

    int srow = tid >> 3;            // 0..31
    int sk   = (tid & 7) * 8;       // 0..56

    f32x4 acc[2];
    acc[0] = (f32x4){0.f, 0.f, 0.f, 0.f};
    acc[1] = (f32x4){0.f, 0.f, 0.f, 0.f};

    for (int k0 = 0; k0 < K; k0 += 64) {
        uint4 av  = *(const uint4*)&A [(size_t)(bm + srow) * K + k0 + sk];
        uint4 bv0 = *(const uint4*)&Bt[(size_t)(bn + srow) * K + k0 + sk];
        uint4 bv1 = *(const uint4*)&Bt[(size_t)(bn + srow + 32) * K + k0 + sk];
        __syncthreads();
        *(uint4*)&As[srow * LDS_STRIDE + sk]        = av;
        *(uint4*)&Bs[srow * LDS_STRIDE + sk]        = bv0;
        *(uint4*)&Bs[(srow + 32) * LDS_STRIDE + sk] = bv1;
        __syncthreads();

#pragma unroll
        for (int s = 0; s < 2; ++s) {
            bf16x8 af = *(const bf16x8*)&As[(it * 16 + (l & 15)) * LDS_STRIDE
                                            + s * 32 + (l >> 4) * 8];
#pragma unroll
            for (int j = 0; j < 2; ++j) {
                bf16x8 bfr = *(const bf16x8*)&Bs[(cb + j * 16 + (l & 15)) * LDS_STRIDE
                                                 + s * 32 + (l >> 4) * 8];
                acc[j] = __builtin_amdgcn_mfma_f32_16x16x32_bf16(af, bfr, acc[j], 0, 0, 0);
            }
        }
    }

    // epilogue: partial dot with W3 over this wave's 32 cols
    int row0 = bm + it * 16 + (l >> 4) * 4;
    float w3v[2], b2v[2];
#pragma unroll
    for (int j = 0; j < 2; ++j) {
        int col = bn + cb + j * 16 + (l & 15);
        w3v[j] = W3[col];
        b2v[j] = bias[col];
    }
#pragma unroll
    for (int r = 0; r < 4; ++r) {
        float s = fmaxf(acc[0][r] + b2v[0], 0.f) * w3v[0]
                + fmaxf(acc[1][r] + b2v[1], 0.f) * w3v[1];
#pragma unroll
        for (int off = 8; off > 0; off >>= 1)
            s += __shfl_xor(s, off);
        if ((l & 15) == 0)
            atomicAdd(&ydeep[row0 + r], s);
    }
}

// ---------------------------------------------------------------------------
// Kernel E: final: out = sigmoid(yfm + relu(ydeep + b3))
// ---------------------------------------------------------------------------
__global__ __launch_bounds__(256) void final_kernel(
    const float* __restrict__ yfm, const float* __restrict__ ydeep,
    const float* __restrict__ b3, float* __restrict__ out)
{
    int b = blockIdx.x * 256 + threadIdx.x;
    if (b >= BATCH) return;
    float yd = fmaxf(ydeep[b] + b3[0], 0.f);
    float x  = yfm[b] + yd;
    out[b] = 1.f / (1.f + expf(-x));
}

// ---------------------------------------------------------------------------
extern "C" void kernel_launch(void* const* d_in, const int* in_sizes, int n_in,
                              void* d_out, int out_size, void* d_ws, size_t ws_size,
                              hipStream_t stream)
{
    const float* numeric  = (const float*)d_in[0];
    const float* cat      = (const float*)d_in[1];
    const float* W_num    = (const float*)d_in[2];
    const float* b_num    = (const float*)d_in[3];
    const float* emb_tab  = (const float*)d_in[4];
    const float* w_fm     = (const float*)d_in[5];
    const float* b_fm     = (const float*)d_in[6];
    const float* W1       = (const float*)d_in[7];
    const float* b1       = (const float*)d_in[8];
    const float* W2       = (const float*)d_in[9];
    const float* b2       = (const float*)d_in[10];
    const float* W3       = (const float*)d_in[11];
    const float* b3       = (const float*)d_in[12];
    float* out = (float*)d_out;
    (void)ws_size; (void)in_sizes; (void)n_in; (void)out_size;

    char* ws = (char*)d_ws;
    float*    yfm    = (float*)   (ws + WS_YFM_OFF);
    float*    ydeep  = (float*)   (ws + WS_YDEEP_OFF);
    ushort_t* embedB = (ushort_t*)(ws + WS_EMBED_OFF);
    ushort_t* h1B    = (ushort_t*)(ws + WS_H1_OFF);
    ushort_t* W1t    = (ushort_t*)(ws + WS_W1T_OFF);
    ushort_t* W2t    = (ushort_t*)(ws + WS_W2T_OFF);

    // A) weight prep + ydeep zero
    prep_kernel<<<(PREP_TOTAL + 255) / 256, 256, 0, stream>>>(
        W1, W2, W1t, W2t, ydeep);
    // B) fused scan + assemble
    scan_assemble_kernel<<<BATCH, 256, 0, stream>>>(
        cat, numeric, W_num, b_num, emb_tab, w_fm, b_fm, embedB, yfm);
    // C) h1 = relu(embed @ W1 + b1) -> bf16
    {
        dim3 grid(H1 / 64, BATCH / 64);
        gemm1_kernel<<<grid, 256, 0, stream>>>(embedB, W1t, b1, h1B);
    }
    // D) ydeep += partial dots of relu(h1 @ W2 + b2) with W3
    {
        dim3 grid(H2 / 64, BATCH / 32);
        gemm2_dot_kernel<<<grid, 256, 0, stream>>>(h1B, W2t, b2, W3, ydeep);
    }
    // E) out = sigmoid(yfm + relu(ydeep + b3))
    final_kernel<<<BATCH / 256, 256, 0, stream>>>(yfm, ydeep, b3, out);
}